// Round 14
// baseline (138.073 us; speedup 1.0000x reference)
//
#include <hip/hip_runtime.h>

// Problem constants
#define IN_F 4096
#define OUT_F 12288
#define BATCH 8
#define NGROUPS 32

// 256 blocks (1/CU), 1024 threads = 16 waves (4/SIMD), 3 consecutive rows/wave.
// x (128 KB) + scale/cc tables (12 KB) staged to LDS once; single barrier.
// NEW vs R11: qweight read in 4 KB SEQUENTIAL bursts per row (superblock of
// 4 chunks, 12 back-to-back loads, single-buffered q[3][4]) to maximize DRAM
// page locality -- R11 interleaved 3 streams at 1 KB granularity.
// Register budget counted: q 48 + acc 24 + w 12 + xb 4 + addr ~20 ~= 110 < 128.
#define ROWS_PER_WAVE 3
#define ROWS_PER_BLOCK 48
#define NBLOCKS (OUT_F / ROWS_PER_BLOCK)  // 256
#define THREADS 1024
#define CHUNK 256
#define NCHUNKS (IN_F / CHUNK)            // 16
#define SB 4                              // chunks per superblock (4 KB/row)
#define NSB (NCHUNKS / SB)                // 4

typedef int v4i __attribute__((ext_vector_type(4)));

__global__ __launch_bounds__(THREADS, 4)   // same config that allocated cleanly in R9/R11
void w4a32_gemv(const float* __restrict__ x,
                const int* __restrict__ qw,
                const float* __restrict__ scales,
                const float* __restrict__ zeros,
                float* __restrict__ out)
{
    __shared__ float xs[BATCH][IN_F];                  // 128 KB
    __shared__ float szs[NGROUPS * ROWS_PER_BLOCK];    // 6 KB scale
    __shared__ float szc[NGROUPS * ROWS_PER_BLOCK];    // 6 KB cc = z - 8*s

    const int tid   = threadIdx.x;
    const int wave  = tid >> 6;
    const int lane  = tid & 63;
    const int rowb  = blockIdx.x * ROWS_PER_BLOCK;
    const int wrow  = wave * ROWS_PER_WAVE;            // 0,3,...,45
    const int klane = lane << 2;

    const int* __restrict__ qbase = qw + (size_t)(rowb + wrow) * IN_F + klane;

    // Issue one superblock: per row, 4 chunk-loads back-to-back
    // (4 KB sequential per row; rows visited in order).
#define ISSUE_SB(Q, s) do {                                                  \
    _Pragma("unroll")                                                        \
    for (int r = 0; r < ROWS_PER_WAVE; ++r)                                  \
        _Pragma("unroll")                                                    \
        for (int c = 0; c < SB; ++c)                                         \
            Q[r][c] = *reinterpret_cast<const v4i*>(                         \
                qbase + r * IN_F + ((s) * SB + c) * CHUNK);                  \
    } while (0)

    v4i q[ROWS_PER_WAVE][SB];   // single buffer, 48 VGPRs
    ISSUE_SB(q, 0);             // in flight while we stage x

    // Stage all of x: 8192 float4 / 1024 threads = 8 each, coalesced.
#pragma unroll
    for (int j = 0; j < 8; ++j) {
        const int idx = tid + j * THREADS;             // 0..8191
        const int b   = idx >> 10;                     // 1024 float4 per batch row
        const int kk  = (idx & 1023) << 2;
        *reinterpret_cast<float4*>(&xs[b][kk]) =
            *reinterpret_cast<const float4*>(&x[b * IN_F + kk]);
    }
    // Stage scale and cc = z - 8*s for this block's 48 rows (32 groups).
#pragma unroll
    for (int j = 0; j < 2; ++j) {
        const int idx = tid + j * THREADS;             // 0..2047
        const int g   = idx >> 6;
        const int r   = idx & 63;
        if (r < ROWS_PER_BLOCK) {
            const float s = scales[g * OUT_F + rowb + r];
            const float z = zeros [g * OUT_F + rowb + r];
            szs[g * ROWS_PER_BLOCK + r] = s;
            szc[g * ROWS_PER_BLOCK + r] = __builtin_fmaf(s, -8.f, z);
        }
    }
    __syncthreads();  // the ONLY barrier

    float acc[ROWS_PER_WAVE][BATCH];
#pragma unroll
    for (int r = 0; r < ROWS_PER_WAVE; ++r)
#pragma unroll
        for (int b = 0; b < BATCH; ++b) acc[r][b] = 0.f;

    for (int s = 0; s < NSB; ++s) {
#pragma unroll
        for (int c = 0; c < SB; ++c) {
            const int cc = s * SB + c;                 // chunk id 0..15
            const int g  = 2 * cc + (lane >> 5);       // quant group of lane's 4 k

            // Dequantize this chunk's 12 weights once (q[*][c] dies here).
            float w[ROWS_PER_WAVE][4];
#pragma unroll
            for (int r = 0; r < ROWS_PER_WAVE; ++r) {
                const float sc = szs[g * ROWS_PER_BLOCK + wrow + r];
                const float cz = szc[g * ROWS_PER_BLOCK + wrow + r];
                w[r][0] = __builtin_fmaf((float)q[r][c][0], sc, cz);
                w[r][1] = __builtin_fmaf((float)q[r][c][1], sc, cz);
                w[r][2] = __builtin_fmaf((float)q[r][c][2], sc, cz);
                w[r][3] = __builtin_fmaf((float)q[r][c][3], sc, cz);
            }

            // After the last chunk's dequant the whole q buffer is dead:
            // issue the next superblock (12 sequential loads) right here.
            if (c == SB - 1 && s + 1 < NSB) ISSUE_SB(q, s + 1);

            // Stream x one float4 at a time (4 live VGPRs for x).
#pragma unroll
            for (int b = 0; b < BATCH; ++b) {
                const float4 xb =
                    *reinterpret_cast<const float4*>(&xs[b][cc * CHUNK + klane]);
#pragma unroll
                for (int r = 0; r < ROWS_PER_WAVE; ++r) {
                    float a = acc[r][b];
                    a = __builtin_fmaf(w[r][0], xb.x, a);
                    a = __builtin_fmaf(w[r][1], xb.y, a);
                    a = __builtin_fmaf(w[r][2], xb.z, a);
                    a = __builtin_fmaf(w[r][3], xb.w, a);
                    acc[r][b] = a;
                }
            }
        }
    }
#undef ISSUE_SB

    // Cross-lane reduction + store (lanes 0..7 hold the 8 batches)
#pragma unroll
    for (int r = 0; r < ROWS_PER_WAVE; ++r) {
        const int n = rowb + wrow + r;
#pragma unroll
        for (int b = 0; b < BATCH; ++b) {
            float v = acc[r][b];
            v += __shfl_xor(v, 32);
            v += __shfl_xor(v, 16);
            v += __shfl_xor(v, 8);
            v += __shfl_xor(v, 4);
            v += __shfl_xor(v, 2);
            v += __shfl_xor(v, 1);
            if (lane == b) out[b * OUT_F + n] = v;
        }
    }
}

extern "C" void kernel_launch(void* const* d_in, const int* in_sizes, int n_in,
                              void* d_out, int out_size, void* d_ws, size_t ws_size,
                              hipStream_t stream) {
    const float* x      = (const float*)d_in[0];
    const int*   qw     = (const int*)d_in[1];
    const float* scales = (const float*)d_in[2];
    const float* zeros  = (const float*)d_in[3];
    float* out = (float*)d_out;

    w4a32_gemv<<<NBLOCKS, THREADS, 0, stream>>>(x, qw, scales, zeros, out);
}

// Round 15
// 42.864 us; speedup vs baseline: 3.2212x; 3.2212x over previous
//
#include <hip/hip_runtime.h>

// Problem constants
#define IN_F 4096
#define OUT_F 12288
#define BATCH 8
#define NGROUPS 32

// 256 blocks (1/CU), 1024 threads = 16 waves (4 per SIMD for TLP),
// 3 consecutive rows per wave, 48 rows/block.
// x (128 KB) + scale/cc tables (12 KB) staged to LDS once; single barrier.
// This is the best-measured configuration (43.2 us, ~4.75 TB/s pure read,
// VGPR=128 clean, no spills). Structures with more in-flight weight regs
// (R8/R10/R12/R13/R14) all flipped regalloc into 64-VGPR + scratch spills.
#define ROWS_PER_WAVE 3
#define ROWS_PER_BLOCK 48
#define NBLOCKS (OUT_F / ROWS_PER_BLOCK)  // 256
#define THREADS 1024
#define CHUNK 256
#define NCHUNKS (IN_F / CHUNK)            // 16

typedef int v4i __attribute__((ext_vector_type(4)));

__global__ __launch_bounds__(THREADS, 4)   // 16 waves/block -> VGPR cap 128 (required)
void w4a32_gemv(const float* __restrict__ x,
                const int* __restrict__ qw,
                const float* __restrict__ scales,
                const float* __restrict__ zeros,
                float* __restrict__ out)
{
    __shared__ float xs[BATCH][IN_F];                  // 128 KB
    __shared__ float szs[NGROUPS * ROWS_PER_BLOCK];    // 6 KB scale
    __shared__ float szc[NGROUPS * ROWS_PER_BLOCK];    // 6 KB cc = z - 8*s

    const int tid   = threadIdx.x;
    const int wave  = tid >> 6;
    const int lane  = tid & 63;
    const int rowb  = blockIdx.x * ROWS_PER_BLOCK;
    const int wrow  = wave * ROWS_PER_WAVE;            // 0,3,...,45
    const int klane = lane << 2;

    const int* __restrict__ qbase = qw + (size_t)(rowb + wrow) * IN_F + klane;

    // Load one 256-k chunk for this wave's 3 rows (1 KB contiguous per row).
#define ISSUE(B, c) do {                                                     \
    _Pragma("unroll")                                                        \
    for (int r = 0; r < ROWS_PER_WAVE; ++r)                                  \
        B[r] = *reinterpret_cast<const v4i*>(qbase + r * IN_F + (c) * CHUNK);\
    } while (0)

    v4i qA[ROWS_PER_WAVE], qB[ROWS_PER_WAVE];
    ISSUE(qA, 0);   // in flight while we stage x

    // Stage all of x: 8192 float4 / 1024 threads = 8 each, coalesced.
#pragma unroll
    for (int j = 0; j < 8; ++j) {
        const int idx = tid + j * THREADS;             // 0..8191
        const int b   = idx >> 10;                     // 1024 float4 per batch row
        const int kk  = (idx & 1023) << 2;
        *reinterpret_cast<float4*>(&xs[b][kk]) =
            *reinterpret_cast<const float4*>(&x[b * IN_F + kk]);
    }
    // Stage scale and cc = z - 8*s for this block's 48 rows (32 groups).
#pragma unroll
    for (int j = 0; j < 2; ++j) {
        const int idx = tid + j * THREADS;             // 0..2047
        const int g   = idx >> 6;
        const int r   = idx & 63;
        if (r < ROWS_PER_BLOCK) {
            const float s = scales[g * OUT_F + rowb + r];
            const float z = zeros [g * OUT_F + rowb + r];
            szs[g * ROWS_PER_BLOCK + r] = s;
            szc[g * ROWS_PER_BLOCK + r] = __builtin_fmaf(s, -8.f, z);
        }
    }
    __syncthreads();  // the ONLY barrier

    float acc[ROWS_PER_WAVE][BATCH];
#pragma unroll
    for (int r = 0; r < ROWS_PER_WAVE; ++r)
#pragma unroll
        for (int b = 0; b < BATCH; ++b) acc[r][b] = 0.f;

#define CONSUME(B, c) do {                                                   \
    const int g = 2 * (c) + (lane >> 5);                                     \
    float4 xr[BATCH];                                                        \
    _Pragma("unroll")                                                        \
    for (int b = 0; b < BATCH; ++b)                                          \
        xr[b] = *reinterpret_cast<const float4*>(&xs[b][(c) * CHUNK + klane]);\
    _Pragma("unroll")                                                        \
    for (int r = 0; r < ROWS_PER_WAVE; ++r) {                                \
        const float s  = szs[g * ROWS_PER_BLOCK + wrow + r];                 \
        const float cc = szc[g * ROWS_PER_BLOCK + wrow + r];                 \
        const float w0 = __builtin_fmaf((float)B[r][0], s, cc);              \
        const float w1 = __builtin_fmaf((float)B[r][1], s, cc);              \
        const float w2 = __builtin_fmaf((float)B[r][2], s, cc);              \
        const float w3 = __builtin_fmaf((float)B[r][3], s, cc);              \
        _Pragma("unroll")                                                    \
        for (int b = 0; b < BATCH; ++b) {                                    \
            float a = acc[r][b];                                             \
            a = __builtin_fmaf(w0, xr[b].x, a);                              \
            a = __builtin_fmaf(w1, xr[b].y, a);                              \
            a = __builtin_fmaf(w2, xr[b].z, a);                              \
            a = __builtin_fmaf(w3, xr[b].w, a);                              \
            acc[r][b] = a;                                                   \
        }                                                                    \
    } } while (0)

    // 2-deep pipeline over 16 chunks; named buffers only.
    for (int c = 0; c < NCHUNKS; c += 2) {
        ISSUE(qB, c + 1);
        CONSUME(qA, c);
        if (c + 2 < NCHUNKS) ISSUE(qA, c + 2);
        CONSUME(qB, c + 1);
    }
#undef ISSUE
#undef CONSUME

    // Cross-lane reduction + store (lanes 0..7 hold the 8 batches)
#pragma unroll
    for (int r = 0; r < ROWS_PER_WAVE; ++r) {
        const int n = rowb + wrow + r;
#pragma unroll
        for (int b = 0; b < BATCH; ++b) {
            float v = acc[r][b];
            v += __shfl_xor(v, 32);
            v += __shfl_xor(v, 16);
            v += __shfl_xor(v, 8);
            v += __shfl_xor(v, 4);
            v += __shfl_xor(v, 2);
            v += __shfl_xor(v, 1);
            if (lane == b) out[b * OUT_F + n] = v;
        }
    }
}

extern "C" void kernel_launch(void* const* d_in, const int* in_sizes, int n_in,
                              void* d_out, int out_size, void* d_ws, size_t ws_size,
                              hipStream_t stream) {
    const float* x      = (const float*)d_in[0];
    const int*   qw     = (const int*)d_in[1];
    const float* scales = (const float*)d_in[2];
    const float* zeros  = (const float*)d_in[3];
    float* out = (float*)d_out;

    w4a32_gemv<<<NBLOCKS, THREADS, 0, stream>>>(x, qw, scales, zeros, out);
}